// Round 9
// baseline (2899.593 us; speedup 1.0000x reference)
//
#include <hip/hip_runtime.h>
#include <stdint.h>

#define H   300
#define HP  320
#define CAP 32     // max incoming bonds per atom (Binomial(400k,1/200k) max ~13)

using bf8 = __attribute__((ext_vector_type(8))) short;   // 8 x bf16
using s4  = __attribute__((ext_vector_type(4))) short;   // 4 x bf16 (8B store)
using f4  = __attribute__((ext_vector_type(4))) float;   // MFMA acc

__device__ __forceinline__ float bf2f(unsigned short u){
    union { unsigned int i; float f; } v; v.i = ((unsigned int)u) << 16; return v.f;
}
__device__ __forceinline__ unsigned short f2bf(float x){
    unsigned int u = __builtin_bit_cast(unsigned int, x);
    u = (u + 0x7FFFu + ((u >> 16) & 1u)) >> 16;   // RNE
    return (unsigned short)u;
}

// Swizzled row layout: element (row,col) of a [rows][320] buffer lives at
//   row*320 + ((col>>3) ^ (row&7))*8 + (col&7)
// For [rows][160] buffers the mask is row&3.
__device__ __forceinline__ long sidx320(long row, int ch){
    return row * HP + ((long)(ch ^ ((int)row & 7)) << 3);
}

// ---------------------------------------------------------------------------
// Incoming-bond bucket list: bucket[a][0..cnt[a]) = bond indices with dst==a
// ---------------------------------------------------------------------------
__global__ void fill_k(const int* __restrict__ b_dst, int* __restrict__ cnt,
                       int* __restrict__ bucket, int nB){
    int e = blockIdx.x * 256 + threadIdx.x;
    if (e >= nB) return;
    int d = b_dst[e];
    int slot = atomicAdd(&cnt[d], 1);
    if (slot < CAP) bucket[(long)d * CAP + slot] = e;
}

// ---------------------------------------------------------------------------
// Weight prep: W [Kact][H] fp32 -> Wt [320][Kp] bf16, transposed + zero-padded
// ---------------------------------------------------------------------------
__global__ void prep_wt(const float* __restrict__ W, unsigned short* __restrict__ Wt,
                        int Kact, int Kp){
    int idx = blockIdx.x * 256 + threadIdx.x;
    if (idx >= 320 * Kp) return;
    int n = idx / Kp, k = idx % Kp;
    float v = (n < H && k < Kact) ? W[(long)k * H + n] : 0.f;
    Wt[idx] = f2bf(v);
}

// W_o [900][300] -> Wt_o [320][960]: k = sec*320+kk maps to W row sec*300+kk
__global__ void prep_wto(const float* __restrict__ W, unsigned short* __restrict__ Wt){
    int idx = blockIdx.x * 256 + threadIdx.x;
    if (idx >= 320 * 960) return;
    int n = idx / 960, k = idx % 960;
    int blk = k / HP, kk = k % HP;
    float v = (n < H && kk < H) ? W[((long)blk * H + kk) * H + n] : 0.f;
    Wt[idx] = f2bf(v);
}

// ---------------------------------------------------------------------------
// Input feature conversion: X fp32 [rows][Kact] -> Y bf16 [rows][160] padded,
// written PRE-SWIZZLED (chunk ^ (row&3)) so GEMM A-loads are contiguous.
// ---------------------------------------------------------------------------
__global__ __launch_bounds__(256)
void conv_in(const float* __restrict__ X, int rows, int Kact,
             unsigned short* __restrict__ Y){
    int t = blockIdx.x * 256 + threadIdx.x;
    if (t >= rows * 20) return;
    int row = t / 20, c = t % 20;
    int k0 = c * 8;
    bf8 v;
    #pragma unroll
    for (int j = 0; j < 8; j++){
        int k = k0 + j;
        float f = (k < Kact) ? X[(long)row * Kact + k] : 0.f;
        v[j] = (short)f2bf(f);
    }
    *(bf8*)(Y + (long)row * 160 + ((c ^ (row & 3)) << 3)) = v;
}

// ---------------------------------------------------------------------------
// Persistent pipelined GEMM: out[rows][320] = epi( [A0|A1|A2][rows][SEC*RL] @ Wt^T )
// A-tiles REG-STAGED: coalesced global_load_dwordx4 (1KB/wave line-filling
// requests -- no global_load_lds 4x line amplification), issued at section
// start, in flight across the K-loop, ds_write'd to the other LDS buffer
// after compute (one barrier per section).
// B: depth-3 register pipeline from L2-resident weights. Grid-stride tiles.
// MFMA operands swapped (computes D^T): 8B contiguous epilogue stores.
// EPI: 0 = relu, 1 = raw, 2 = relu + b_o.  Output written pre-swizzled.
// ---------------------------------------------------------------------------
template<int RL, int SEC, int EPI>
__global__ __launch_bounds__(256, 2)
void gemm_p(const unsigned short* __restrict__ A0,
            const unsigned short* __restrict__ A1,
            const unsigned short* __restrict__ A2,
            const unsigned short* __restrict__ Wt,   // [320][SEC*RL]
            const float* __restrict__ b_o,
            unsigned short* __restrict__ outb,       // [rows][320] swizzled
            int nTiles)
{
    constexpr int KS     = RL / 32;        // K-steps per section
    constexpr int XM     = (RL == 320) ? 7 : 3;
    constexpr int TILEB  = 64 * RL * 2;    // bytes per LDS buffer
    constexpr int ROUNDS = TILEB / 4096;   // 256 thr x 16B per round
    constexpr int Ktot   = SEC * RL;

    __shared__ char lds[2 * TILEB];

    const int tid  = threadIdx.x;
    const int w    = tid >> 6;
    const int lane = tid & 63;
    const int lr   = lane & 15;
    const int g    = lane >> 4;

    const unsigned short* Ap[3] = {A0, A1, A2};

    bf8 st[ROUNDS];                        // staging registers (40/20 VGPR)
    auto loadA = [&](const unsigned short* src, int rowBase){
        const char* g0 = (const char*)(src + (long)rowBase * RL) + tid * 16;
        #pragma unroll
        for (int rd = 0; rd < ROUNDS; rd++)
            st[rd] = *(const bf8*)(g0 + rd * 4096);
    };
    auto writeA = [&](int buf){
        char* l0 = lds + buf * TILEB + tid * 16;
        #pragma unroll
        for (int rd = 0; rd < ROUNDS; rd++)
            *(bf8*)(l0 + rd * 4096) = st[rd];
    };

    auto aoff = [&](int buf, int row, int chunk)->int {
        return buf * TILEB + row * (RL * 2) + (((chunk) ^ (row & XM)) << 4);
    };

    bf8 bb[3][5];
    auto loadB = [&](int ks, int slot){
        #pragma unroll
        for (int n = 0; n < 5; n++)
            bb[slot][n] = *(const bf8*)(Wt + (long)(w * 80 + n * 16 + lr) * Ktot + ks * 32 + g * 8);
    };

    f4 acc[4][5];

    int tile = blockIdx.x;
    if (tile >= nTiles) return;
    loadA(Ap[0], tile * 64);
    writeA(0);                             // implicit vmcnt wait
    __syncthreads();

    int buf = 0;
    for (; tile < nTiles; tile += gridDim.x){
        #pragma unroll
        for (int m = 0; m < 4; m++)
            #pragma unroll
            for (int n = 0; n < 5; n++)
                acc[m][n] = (f4){0.f, 0.f, 0.f, 0.f};

        #pragma unroll
        for (int sec = 0; sec < SEC; ++sec){
            // issue next unit's global loads NOW (land during the K-loop)
            int ns = sec + 1, ntile = tile;
            if (ns == SEC){ ns = 0; ntile = tile + (int)gridDim.x; }
            const bool haveNext = (ntile < nTiles);
            if (haveNext) loadA(Ap[ns], ntile * 64);

            loadB(sec * KS + 0, 0);
            loadB(sec * KS + 1, 1);
            loadB(sec * KS + 2, 2);

            #pragma unroll
            for (int i = 0; i < KS; i++){
                bf8 af[4];
                #pragma unroll
                for (int m = 0; m < 4; m++)
                    af[m] = *(const bf8*)(lds + aoff(buf, m * 16 + lr, i * 4 + g));
                // swapped operands: D^T -> lane holds row (lane&15), 4 cols
                #pragma unroll
                for (int m = 0; m < 4; m++)
                    #pragma unroll
                    for (int n = 0; n < 5; n++)
                        acc[m][n] = __builtin_amdgcn_mfma_f32_16x16x32_bf16(bb[i % 3][n], af[m], acc[m][n], 0, 0, 0);
                if (i + 3 < KS) loadB(sec * KS + i + 3, i % 3);
            }

            if (sec == SEC - 1){
                #pragma unroll
                for (int m = 0; m < 4; m++){
                    const long row = tile * 64 + m * 16 + lr;
                    const long rbase = row * HP;
                    const int rx = (int)row & 7;
                    #pragma unroll
                    for (int n = 0; n < 5; n++){
                        const int colBase = w * 80 + n * 16 + g * 4;
                        s4 v4;
                        #pragma unroll
                        for (int q = 0; q < 4; q++){
                            int col = colBase + q;
                            float v = acc[m][n][q];
                            if constexpr (EPI == 2) v += (col < H ? b_o[col] : 0.f);
                            if constexpr (EPI != 1) v = fmaxf(v, 0.f);
                            v4[q] = (short)f2bf(v);
                        }
                        int ch = colBase >> 3;
                        *(s4*)(outb + rbase + ((long)(ch ^ rx) << 3) + (colBase & 7)) = v4;
                    }
                }
            }

            // stage next unit into the other buffer (vmcnt wait is implicit;
            // loads landed during the K-loop). Prev readers of buf^1 finished
            // before the barrier at the end of the previous section.
            if (haveNext) writeA(buf ^ 1);
            __syncthreads();
            buf ^= 1;
        }
    }
}

// ---------------------------------------------------------------------------
// comb: msg'[e] = relu(bond_in[e] + sum_{j in bucket[src[e]]} MW[j] - MW[rev[e]])
// thread = (bond, 16B chunk); all buffers in swizzled layout.
// ---------------------------------------------------------------------------
__global__ __launch_bounds__(256)
void comb_k(const unsigned short* __restrict__ MW,
            const unsigned short* __restrict__ bond_in,
            const int* __restrict__ b_src, const int* __restrict__ b2revb,
            const int* __restrict__ cnt, const int* __restrict__ bucket,
            unsigned short* __restrict__ out, int nB){
    int t = blockIdx.x * 256 + threadIdx.x;
    if (t >= nB * 40) return;
    int e = t / 40, ch = t % 40;
    int s   = b_src[e];
    int rev = b2revb[e];
    int dg = cnt[s]; if (dg > CAP) dg = CAP;
    long base = (long)s * CAP;
    int be0 = 0, be1 = 0, be2 = 0, be3 = 0;
    if (dg > 0) be0 = bucket[base + 0];
    if (dg > 1) be1 = bucket[base + 1];
    if (dg > 2) be2 = bucket[base + 2];
    if (dg > 3) be3 = bucket[base + 3];
    bf8 bi = *(const bf8*)(bond_in + sidx320(e, ch));
    bf8 rv = *(const bf8*)(MW + sidx320(rev, ch));
    bf8 m0, m1, m2, m3;
    if (dg > 0) m0 = *(const bf8*)(MW + sidx320(be0, ch));
    if (dg > 1) m1 = *(const bf8*)(MW + sidx320(be1, ch));
    if (dg > 2) m2 = *(const bf8*)(MW + sidx320(be2, ch));
    if (dg > 3) m3 = *(const bf8*)(MW + sidx320(be3, ch));
    float sacc[8];
    #pragma unroll
    for (int q = 0; q < 8; q++)
        sacc[q] = bf2f((unsigned short)bi[q]) - bf2f((unsigned short)rv[q]);
    auto addv = [&](bf8 mm){
        #pragma unroll
        for (int q = 0; q < 8; q++) sacc[q] += bf2f((unsigned short)mm[q]);
    };
    if (dg > 0) addv(m0);
    if (dg > 1) addv(m1);
    if (dg > 2) addv(m2);
    if (dg > 3) addv(m3);
    for (int j = 4; j < dg; ++j){
        int be = bucket[base + j];
        addv(*(const bf8*)(MW + sidx320(be, ch)));
    }
    bf8 v;
    #pragma unroll
    for (int q = 0; q < 8; q++) v[q] = (short)f2bf(fmaxf(sacc[q], 0.f));
    *(bf8*)(out + sidx320(e, ch)) = v;
}

// ---------------------------------------------------------------------------
// a_msg[a] = sum of msg rows with dst==a; also prod[a] = a_msg[a] * input_atom[a]
// ---------------------------------------------------------------------------
__global__ __launch_bounds__(256)
void amsg_k(const unsigned short* __restrict__ msg, const int* __restrict__ cnt,
            const int* __restrict__ bucket,
            const unsigned short* __restrict__ input_atom,
            unsigned short* __restrict__ amsg, unsigned short* __restrict__ prod,
            int nA){
    int t = blockIdx.x * 256 + threadIdx.x;
    if (t >= nA * 40) return;
    int a = t / 40, ch = t % 40;
    int dg = cnt[a]; if (dg > CAP) dg = CAP;
    long base = (long)a * CAP;
    int be0 = 0, be1 = 0, be2 = 0, be3 = 0;
    if (dg > 0) be0 = bucket[base + 0];
    if (dg > 1) be1 = bucket[base + 1];
    if (dg > 2) be2 = bucket[base + 2];
    if (dg > 3) be3 = bucket[base + 3];
    bf8 ia = *(const bf8*)(input_atom + sidx320(a, ch));
    bf8 m0, m1, m2, m3;
    if (dg > 0) m0 = *(const bf8*)(msg + sidx320(be0, ch));
    if (dg > 1) m1 = *(const bf8*)(msg + sidx320(be1, ch));
    if (dg > 2) m2 = *(const bf8*)(msg + sidx320(be2, ch));
    if (dg > 3) m3 = *(const bf8*)(msg + sidx320(be3, ch));
    float s[8];
    #pragma unroll
    for (int q = 0; q < 8; q++) s[q] = 0.f;
    auto addv = [&](bf8 mm){
        #pragma unroll
        for (int q = 0; q < 8; q++) s[q] += bf2f((unsigned short)mm[q]);
    };
    if (dg > 0) addv(m0);
    if (dg > 1) addv(m1);
    if (dg > 2) addv(m2);
    if (dg > 3) addv(m3);
    for (int j = 4; j < dg; ++j)
        addv(*(const bf8*)(msg + sidx320(bucket[base + j], ch)));
    bf8 va, vp;
    #pragma unroll
    for (int q = 0; q < 8; q++){
        va[q] = (short)f2bf(s[q]);
        vp[q] = (short)f2bf(s[q] * bf2f((unsigned short)ia[q]));
    }
    *(bf8*)(amsg + sidx320(a, ch)) = va;
    *(bf8*)(prod + sidx320(a, ch)) = vp;
}

// ---------------------------------------------------------------------------
// Readout: per-molecule mean over sorted mol_ids (binary-search range).
// ---------------------------------------------------------------------------
__global__ __launch_bounds__(320)
void readout_k(const unsigned short* __restrict__ atom_h,
               const int* __restrict__ mol_ids, int nAtoms,
               float* __restrict__ out){
    int m = blockIdx.x;
    int t = threadIdx.x;
    int lo = 0, hi = nAtoms;
    while (lo < hi){ int mid = (lo + hi) >> 1; if (mol_ids[mid] < m) lo = mid + 1; else hi = mid; }
    int lo2 = lo, hi2 = nAtoms;
    while (lo2 < hi2){ int mid = (lo2 + hi2) >> 1; if (mol_ids[mid] < m + 1) lo2 = mid + 1; else hi2 = mid; }
    if (t < H){
        int ch = t >> 3, j = t & 7;
        float s = 0.f;
        for (int a = lo; a < lo2; ++a)
            s += bf2f(atom_h[sidx320(a, ch) + j]);
        int c2 = lo2 - lo;
        out[(long)m * H + t] = s / (float)(c2 > 0 ? c2 : 1);
    }
}

// ---------------------------------------------------------------------------
extern "C" void kernel_launch(void* const* d_in, const int* in_sizes, int n_in,
                              void* d_out, int out_size, void* d_ws, size_t ws_size,
                              hipStream_t stream){
    const float* f_atoms  = (const float*)d_in[0];
    const float* f_bonds  = (const float*)d_in[1];
    const float* W_i_atom = (const float*)d_in[2];
    const float* W_i_bond = (const float*)d_in[3];
    const float* W_h      = (const float*)d_in[4];
    const float* W_o      = (const float*)d_in[5];
    const float* b_o      = (const float*)d_in[6];
    const int* b_src   = (const int*)d_in[7];
    const int* b_dst   = (const int*)d_in[8];
    const int* b2revb  = (const int*)d_in[9];
    const int* mol_ids = (const int*)d_in[10];

    const int nA = in_sizes[10];          // 200000
    const int nB = in_sizes[7];           // 400000
    const int nM = out_size / H;          // 4096

    char* p = (char*)d_ws;
    auto alloc = [&](size_t bytes){ char* q = p; p += (bytes + 255) & ~(size_t)255; return q; };
    unsigned short* Wt_ia = (unsigned short*)alloc((size_t)320 * 160 * 2);
    unsigned short* Wt_ib = (unsigned short*)alloc((size_t)320 * 160 * 2);
    unsigned short* Wt_h  = (unsigned short*)alloc((size_t)3 * 320 * 320 * 2);
    unsigned short* Wt_o  = (unsigned short*)alloc((size_t)320 * 960 * 2);
    int* cnt    = (int*)alloc((size_t)nA * 4);
    int* bucket = (int*)alloc((size_t)nA * CAP * 4);
    unsigned short* input_atom = (unsigned short*)alloc((size_t)nA * HP * 2);
    unsigned short* input_bond = (unsigned short*)alloc((size_t)nB * HP * 2);
    unsigned short* msgA = (unsigned short*)alloc((size_t)nB * HP * 2);
    unsigned short* MW   = (unsigned short*)alloc((size_t)nB * HP * 2);
    // aliases into dead regions:
    unsigned short* fa_bf  = MW;                                  // [nA][160], dead before MW first written
    unsigned short* fb_bf  = MW + (size_t)nA * 160;               // [nB][160]
    unsigned short* amsg   = MW;                                  // MW dead after comb3
    unsigned short* prod   = MW + (size_t)nA * HP;
    unsigned short* atom_h = input_bond;                          // dead after comb3

    if ((size_t)(p - (char*)d_ws) > ws_size) return;  // diagnostic: ws too small

    // adjacency buckets
    hipMemsetAsync(cnt, 0, (size_t)nA * 4, stream);
    fill_k<<<dim3((nB + 255) / 256), dim3(256), 0, stream>>>(b_dst, cnt, bucket, nB);

    // weight prep + input conversion (inputs pre-swizzled)
    prep_wt<<<dim3((320*160 + 255)/256), dim3(256), 0, stream>>>(W_i_atom, Wt_ia, 133, 160);
    prep_wt<<<dim3((320*160 + 255)/256), dim3(256), 0, stream>>>(W_i_bond, Wt_ib, 147, 160);
    for (int d = 0; d < 3; d++)
        prep_wt<<<dim3((320*320 + 255)/256), dim3(256), 0, stream>>>(
            W_h + (size_t)d * H * H, Wt_h + (size_t)d * 320 * 320, 300, 320);
    prep_wto<<<dim3((320*960 + 255)/256), dim3(256), 0, stream>>>(W_o, Wt_o);
    conv_in<<<dim3((nA*20 + 255)/256), dim3(256), 0, stream>>>(f_atoms, nA, 133, fa_bf);
    conv_in<<<dim3((nB*20 + 255)/256), dim3(256), 0, stream>>>(f_bonds, nB, 147, fb_bf);

    const int tilesA = nA / 64, tilesB = nB / 64;

    // input projections
    gemm_p<160,1,0><<<dim3(1024), dim3(256), 0, stream>>>(
        fa_bf, nullptr, nullptr, Wt_ia, nullptr, input_atom, tilesA);
    gemm_p<160,1,0><<<dim3(1024), dim3(256), 0, stream>>>(
        fb_bf, nullptr, nullptr, Wt_ib, nullptr, input_bond, tilesB);

    // message steps: MW = msg @ W_h[d]; msg' = relu(bond_in + bucket-sum - rev)
    const int combGrid = (nB * 40 + 255) / 256;
    const unsigned short* msg_cur = input_bond;
    for (int d = 0; d < 3; d++){
        gemm_p<320,1,1><<<dim3(512), dim3(256), 0, stream>>>(
            msg_cur, nullptr, nullptr, Wt_h + (size_t)d * 320 * 320, nullptr, MW, tilesB);
        comb_k<<<dim3(combGrid), dim3(256), 0, stream>>>(
            MW, input_bond, b_src, b2revb, cnt, bucket, msgA, nB);
        msg_cur = msgA;
    }

    // final per-atom aggregation + product (bf16, swizzled)
    amsg_k<<<dim3((nA * 40 + 255) / 256), dim3(256), 0, stream>>>(
        msgA, cnt, bucket, input_atom, amsg, prod, nA);

    // atom_h = relu([input_atom | amsg | input_atom*amsg] @ W_o + b_o)
    gemm_p<320,3,2><<<dim3(512), dim3(256), 0, stream>>>(
        input_atom, amsg, prod, Wt_o, b_o, atom_h, tilesA);

    // per-molecule mean
    readout_k<<<dim3(nM), dim3(320), 0, stream>>>(atom_h, mol_ids, nA, (float*)d_out);
}

// Round 10
// 2769.018 us; speedup vs baseline: 1.0472x; 1.0472x over previous
//
#include <hip/hip_runtime.h>
#include <stdint.h>

#define H   300
#define HP  320
#define CAP 32     // max incoming bonds per atom (Binomial(400k,1/200k) max ~13)

using bf8 = __attribute__((ext_vector_type(8))) short;   // 8 x bf16
using s4  = __attribute__((ext_vector_type(4))) short;   // 4 x bf16 (8B store)
using f4  = __attribute__((ext_vector_type(4))) float;   // MFMA acc

__device__ __forceinline__ float bf2f(unsigned short u){
    union { unsigned int i; float f; } v; v.i = ((unsigned int)u) << 16; return v.f;
}
__device__ __forceinline__ unsigned short f2bf(float x){
    unsigned int u = __builtin_bit_cast(unsigned int, x);
    u = (u + 0x7FFFu + ((u >> 16) & 1u)) >> 16;   // RNE
    return (unsigned short)u;
}

// ---------------------------------------------------------------------------
// Incoming-bond bucket list: bucket[a][0..cnt[a]) = bond indices with dst==a
// ---------------------------------------------------------------------------
__global__ void fill_k(const int* __restrict__ b_dst, int* __restrict__ cnt,
                       int* __restrict__ bucket, int nB){
    int e = blockIdx.x * 256 + threadIdx.x;
    if (e >= nB) return;
    int d = b_dst[e];
    int slot = atomicAdd(&cnt[d], 1);
    if (slot < CAP) bucket[(long)d * CAP + slot] = e;
}

// ---------------------------------------------------------------------------
// Weight prep: W [Kact][H] fp32 -> Wt [320][Kp] bf16, transposed + zero-padded
// ---------------------------------------------------------------------------
__global__ void prep_wt(const float* __restrict__ W, unsigned short* __restrict__ Wt,
                        int Kact, int Kp){
    int idx = blockIdx.x * 256 + threadIdx.x;
    if (idx >= 320 * Kp) return;
    int n = idx / Kp, k = idx % Kp;
    float v = (n < H && k < Kact) ? W[(long)k * H + n] : 0.f;
    Wt[idx] = f2bf(v);
}

// W_o [900][300] -> Wt_o [320][960]: k = sec*320+kk maps to W row sec*300+kk
__global__ void prep_wto(const float* __restrict__ W, unsigned short* __restrict__ Wt){
    int idx = blockIdx.x * 256 + threadIdx.x;
    if (idx >= 320 * 960) return;
    int n = idx / 960, k = idx % 960;
    int blk = k / HP, kk = k % HP;
    float v = (n < H && kk < H) ? W[((long)blk * H + kk) * H + n] : 0.f;
    Wt[idx] = f2bf(v);
}

// ---------------------------------------------------------------------------
// Input feature conversion: X fp32 [rows][Kact] -> Y bf16 [rows][160] padded
// (linear layout)
// ---------------------------------------------------------------------------
__global__ __launch_bounds__(256)
void conv_in(const float* __restrict__ X, int rows, int Kact,
             unsigned short* __restrict__ Y){
    int t = blockIdx.x * 256 + threadIdx.x;
    if (t >= rows * 20) return;
    int row = t / 20, c = t % 20;
    int k0 = c * 8;
    bf8 v;
    #pragma unroll
    for (int j = 0; j < 8; j++){
        int k = k0 + j;
        float f = (k < Kact) ? X[(long)row * Kact + k] : 0.f;
        v[j] = (short)f2bf(f);
    }
    *(bf8*)(Y + (long)row * 160 + k0) = v;
}

// ---------------------------------------------------------------------------
// Register-direct GEMM (no LDS, no barriers):
//   out[rows][320] = epi( [A0|A1|A2][rows][SEC*RL] @ Wt^T )
// Swapped MFMA (D^T): lane fragment of A = 16B of one row at one k-chunk,
// loaded STRAIGHT from global (wave reads 16 rows x 64B aligned segments).
// A hits HBM once, L2 for the 4-wave re-reads. B rows (L2-resident weights)
// via per-K-step 2-deep register pipeline. af 2-deep. Everything else is
// hidden by TLP (no block-level sync at all).
// EPI: 0 = relu, 1 = raw, 2 = relu + b_o.  All buffers LINEAR layout.
// ---------------------------------------------------------------------------
template<int RL, int SEC, int EPI>
__global__ __launch_bounds__(256, 2)
void gemm_r(const unsigned short* __restrict__ A0,
            const unsigned short* __restrict__ A1,
            const unsigned short* __restrict__ A2,
            const unsigned short* __restrict__ Wt,   // [320][SEC*RL]
            const float* __restrict__ b_o,
            unsigned short* __restrict__ outb,       // [rows][320]
            int nTiles)
{
    constexpr int KS   = RL / 32;          // K-steps per section
    constexpr int TS   = SEC * KS;         // total K-steps
    constexpr int Ktot = SEC * RL;

    const int tid  = threadIdx.x;
    const int w    = tid >> 6;             // wave -> N stripe of 80
    const int lane = tid & 63;
    const int lr   = lane & 15;
    const int g    = lane >> 4;

    int tile = blockIdx.x;
    if (tile >= nTiles) return;
    const long rowBase = (long)tile * 64;

    const unsigned short* Ap[3] = {A0, A1, A2};

    // B row pointers: 5 rows per wave (cols w*80 + n*16 + lr), chunk g
    const unsigned short* bptr[5];
    #pragma unroll
    for (int n = 0; n < 5; n++)
        bptr[n] = Wt + (long)(w * 80 + n * 16 + lr) * Ktot + g * 8;

    bf8 af[2][4];
    bf8 bb[2][5];

    auto loadA = [&](int t, bf8 (&dst)[4]){
        const unsigned short* base = Ap[t / KS] + rowBase * RL
                                   + (long)(t % KS) * 32 + g * 8;
        #pragma unroll
        for (int m = 0; m < 4; m++)
            dst[m] = *(const bf8*)(base + (long)(m * 16 + lr) * RL);
    };
    auto loadB = [&](int t, bf8 (&dst)[5]){
        #pragma unroll
        for (int n = 0; n < 5; n++)
            dst[n] = *(const bf8*)(bptr[n] + (long)t * 32);
    };

    f4 acc[4][5];
    #pragma unroll
    for (int m = 0; m < 4; m++)
        #pragma unroll
        for (int n = 0; n < 5; n++)
            acc[m][n] = (f4){0.f, 0.f, 0.f, 0.f};

    loadA(0, af[0]); loadB(0, bb[0]);
    loadA(1, af[1]); loadB(1, bb[1]);

    #pragma unroll
    for (int t = 0; t < TS; t++){
        // consume current step, then immediately re-issue buffer for t+2
        #pragma unroll
        for (int m = 0; m < 4; m++)
            #pragma unroll
            for (int n = 0; n < 5; n++)
                acc[m][n] = __builtin_amdgcn_mfma_f32_16x16x32_bf16(
                    bb[t & 1][n], af[t & 1][m], acc[m][n], 0, 0, 0);
        if (t + 2 < TS){ loadA(t + 2, af[t & 1]); loadB(t + 2, bb[t & 1]); }
    }

    // epilogue: D^T -> lane holds output row lr(+16m), 4 consecutive cols
    #pragma unroll
    for (int m = 0; m < 4; m++){
        const long row = rowBase + m * 16 + lr;
        #pragma unroll
        for (int n = 0; n < 5; n++){
            const int colBase = w * 80 + n * 16 + g * 4;
            s4 v4;
            #pragma unroll
            for (int q = 0; q < 4; q++){
                int col = colBase + q;
                float v = acc[m][n][q];
                if constexpr (EPI == 2) v += (col < H ? b_o[col] : 0.f);
                if constexpr (EPI != 1) v = fmaxf(v, 0.f);
                v4[q] = (short)f2bf(v);
            }
            *(s4*)(outb + row * HP + colBase) = v4;
        }
    }
}

// ---------------------------------------------------------------------------
// comb: msg'[e] = relu(bond_in[e] + sum_{j in bucket[src[e]]} MW[j] - MW[rev[e]])
// thread = (bond, 16B chunk); 6 independent loads in flight. Linear layout.
// ---------------------------------------------------------------------------
__global__ __launch_bounds__(256)
void comb_k(const unsigned short* __restrict__ MW,
            const unsigned short* __restrict__ bond_in,
            const int* __restrict__ b_src, const int* __restrict__ b2revb,
            const int* __restrict__ cnt, const int* __restrict__ bucket,
            unsigned short* __restrict__ out, int nB){
    int t = blockIdx.x * 256 + threadIdx.x;
    if (t >= nB * 40) return;
    int e = t / 40, ch = t % 40;
    int k0 = ch * 8;
    int s   = b_src[e];
    int rev = b2revb[e];
    int dg = cnt[s]; if (dg > CAP) dg = CAP;
    long base = (long)s * CAP;
    int be0 = 0, be1 = 0, be2 = 0, be3 = 0;
    if (dg > 0) be0 = bucket[base + 0];
    if (dg > 1) be1 = bucket[base + 1];
    if (dg > 2) be2 = bucket[base + 2];
    if (dg > 3) be3 = bucket[base + 3];
    bf8 bi = *(const bf8*)(bond_in + (long)e * HP + k0);
    bf8 rv = *(const bf8*)(MW + (long)rev * HP + k0);
    bf8 m0, m1, m2, m3;
    if (dg > 0) m0 = *(const bf8*)(MW + (long)be0 * HP + k0);
    if (dg > 1) m1 = *(const bf8*)(MW + (long)be1 * HP + k0);
    if (dg > 2) m2 = *(const bf8*)(MW + (long)be2 * HP + k0);
    if (dg > 3) m3 = *(const bf8*)(MW + (long)be3 * HP + k0);
    float sacc[8];
    #pragma unroll
    for (int q = 0; q < 8; q++)
        sacc[q] = bf2f((unsigned short)bi[q]) - bf2f((unsigned short)rv[q]);
    auto addv = [&](bf8 mm){
        #pragma unroll
        for (int q = 0; q < 8; q++) sacc[q] += bf2f((unsigned short)mm[q]);
    };
    if (dg > 0) addv(m0);
    if (dg > 1) addv(m1);
    if (dg > 2) addv(m2);
    if (dg > 3) addv(m3);
    for (int j = 4; j < dg; ++j){
        int be = bucket[base + j];
        addv(*(const bf8*)(MW + (long)be * HP + k0));
    }
    bf8 v;
    #pragma unroll
    for (int q = 0; q < 8; q++) v[q] = (short)f2bf(fmaxf(sacc[q], 0.f));
    *(bf8*)(out + (long)e * HP + k0) = v;
}

// ---------------------------------------------------------------------------
// a_msg[a] = sum of msg rows with dst==a; also prod[a] = a_msg[a] * input_atom[a]
// ---------------------------------------------------------------------------
__global__ __launch_bounds__(256)
void amsg_k(const unsigned short* __restrict__ msg, const int* __restrict__ cnt,
            const int* __restrict__ bucket,
            const unsigned short* __restrict__ input_atom,
            unsigned short* __restrict__ amsg, unsigned short* __restrict__ prod,
            int nA){
    int t = blockIdx.x * 256 + threadIdx.x;
    if (t >= nA * 40) return;
    int a = t / 40, ch = t % 40;
    int k0 = ch * 8;
    int dg = cnt[a]; if (dg > CAP) dg = CAP;
    long base = (long)a * CAP;
    int be0 = 0, be1 = 0, be2 = 0, be3 = 0;
    if (dg > 0) be0 = bucket[base + 0];
    if (dg > 1) be1 = bucket[base + 1];
    if (dg > 2) be2 = bucket[base + 2];
    if (dg > 3) be3 = bucket[base + 3];
    bf8 ia = *(const bf8*)(input_atom + (long)a * HP + k0);
    bf8 m0, m1, m2, m3;
    if (dg > 0) m0 = *(const bf8*)(msg + (long)be0 * HP + k0);
    if (dg > 1) m1 = *(const bf8*)(msg + (long)be1 * HP + k0);
    if (dg > 2) m2 = *(const bf8*)(msg + (long)be2 * HP + k0);
    if (dg > 3) m3 = *(const bf8*)(msg + (long)be3 * HP + k0);
    float s[8];
    #pragma unroll
    for (int q = 0; q < 8; q++) s[q] = 0.f;
    auto addv = [&](bf8 mm){
        #pragma unroll
        for (int q = 0; q < 8; q++) s[q] += bf2f((unsigned short)mm[q]);
    };
    if (dg > 0) addv(m0);
    if (dg > 1) addv(m1);
    if (dg > 2) addv(m2);
    if (dg > 3) addv(m3);
    for (int j = 4; j < dg; ++j)
        addv(*(const bf8*)(msg + (long)bucket[base + j] * HP + k0));
    bf8 va, vp;
    #pragma unroll
    for (int q = 0; q < 8; q++){
        va[q] = (short)f2bf(s[q]);
        vp[q] = (short)f2bf(s[q] * bf2f((unsigned short)ia[q]));
    }
    *(bf8*)(amsg + (long)a * HP + k0) = va;
    *(bf8*)(prod + (long)a * HP + k0) = vp;
}

// ---------------------------------------------------------------------------
// Readout: per-molecule mean over sorted mol_ids (binary-search range)
// ---------------------------------------------------------------------------
__global__ __launch_bounds__(320)
void readout_k(const unsigned short* __restrict__ atom_h,
               const int* __restrict__ mol_ids, int nAtoms,
               float* __restrict__ out){
    int m = blockIdx.x;
    int t = threadIdx.x;
    int lo = 0, hi = nAtoms;
    while (lo < hi){ int mid = (lo + hi) >> 1; if (mol_ids[mid] < m) lo = mid + 1; else hi = mid; }
    int lo2 = lo, hi2 = nAtoms;
    while (lo2 < hi2){ int mid = (lo2 + hi2) >> 1; if (mol_ids[mid] < m + 1) lo2 = mid + 1; else hi2 = mid; }
    if (t < H){
        float s = 0.f;
        for (int a = lo; a < lo2; ++a) s += bf2f(atom_h[(long)a * HP + t]);
        int c2 = lo2 - lo;
        out[(long)m * H + t] = s / (float)(c2 > 0 ? c2 : 1);
    }
}

// ---------------------------------------------------------------------------
extern "C" void kernel_launch(void* const* d_in, const int* in_sizes, int n_in,
                              void* d_out, int out_size, void* d_ws, size_t ws_size,
                              hipStream_t stream){
    const float* f_atoms  = (const float*)d_in[0];
    const float* f_bonds  = (const float*)d_in[1];
    const float* W_i_atom = (const float*)d_in[2];
    const float* W_i_bond = (const float*)d_in[3];
    const float* W_h      = (const float*)d_in[4];
    const float* W_o      = (const float*)d_in[5];
    const float* b_o      = (const float*)d_in[6];
    const int* b_src   = (const int*)d_in[7];
    const int* b_dst   = (const int*)d_in[8];
    const int* b2revb  = (const int*)d_in[9];
    const int* mol_ids = (const int*)d_in[10];

    const int nA = in_sizes[10];          // 200000
    const int nB = in_sizes[7];           // 400000
    const int nM = out_size / H;          // 4096

    char* p = (char*)d_ws;
    auto alloc = [&](size_t bytes){ char* q = p; p += (bytes + 255) & ~(size_t)255; return q; };
    unsigned short* Wt_ia = (unsigned short*)alloc((size_t)320 * 160 * 2);
    unsigned short* Wt_ib = (unsigned short*)alloc((size_t)320 * 160 * 2);
    unsigned short* Wt_h  = (unsigned short*)alloc((size_t)3 * 320 * 320 * 2);
    unsigned short* Wt_o  = (unsigned short*)alloc((size_t)320 * 960 * 2);
    int* cnt    = (int*)alloc((size_t)nA * 4);
    int* bucket = (int*)alloc((size_t)nA * CAP * 4);
    unsigned short* input_atom = (unsigned short*)alloc((size_t)nA * HP * 2);
    unsigned short* input_bond = (unsigned short*)alloc((size_t)nB * HP * 2);
    unsigned short* msgA = (unsigned short*)alloc((size_t)nB * HP * 2);
    unsigned short* MW   = (unsigned short*)alloc((size_t)nB * HP * 2);
    // aliases into dead regions:
    unsigned short* fa_bf  = MW;                                  // [nA][160], dead before MW first written
    unsigned short* fb_bf  = MW + (size_t)nA * 160;               // [nB][160]
    unsigned short* amsg   = MW;                                  // MW dead after comb3
    unsigned short* prod   = MW + (size_t)nA * HP;
    unsigned short* atom_h = input_bond;                          // dead after comb3

    if ((size_t)(p - (char*)d_ws) > ws_size) return;  // diagnostic: ws too small

    // adjacency buckets
    hipMemsetAsync(cnt, 0, (size_t)nA * 4, stream);
    fill_k<<<dim3((nB + 255) / 256), dim3(256), 0, stream>>>(b_dst, cnt, bucket, nB);

    // weight prep + input conversion
    prep_wt<<<dim3((320*160 + 255)/256), dim3(256), 0, stream>>>(W_i_atom, Wt_ia, 133, 160);
    prep_wt<<<dim3((320*160 + 255)/256), dim3(256), 0, stream>>>(W_i_bond, Wt_ib, 147, 160);
    for (int d = 0; d < 3; d++)
        prep_wt<<<dim3((320*320 + 255)/256), dim3(256), 0, stream>>>(
            W_h + (size_t)d * H * H, Wt_h + (size_t)d * 320 * 320, 300, 320);
    prep_wto<<<dim3((320*960 + 255)/256), dim3(256), 0, stream>>>(W_o, Wt_o);
    conv_in<<<dim3((nA*20 + 255)/256), dim3(256), 0, stream>>>(f_atoms, nA, 133, fa_bf);
    conv_in<<<dim3((nB*20 + 255)/256), dim3(256), 0, stream>>>(f_bonds, nB, 147, fb_bf);

    const int tilesA = nA / 64, tilesB = nB / 64;

    // input projections
    gemm_r<160,1,0><<<dim3(tilesA), dim3(256), 0, stream>>>(
        fa_bf, nullptr, nullptr, Wt_ia, nullptr, input_atom, tilesA);
    gemm_r<160,1,0><<<dim3(tilesB), dim3(256), 0, stream>>>(
        fb_bf, nullptr, nullptr, Wt_ib, nullptr, input_bond, tilesB);

    // message steps: MW = msg @ W_h[d]; msg' = relu(bond_in + bucket-sum - rev)
    const int combGrid = (nB * 40 + 255) / 256;
    const unsigned short* msg_cur = input_bond;
    for (int d = 0; d < 3; d++){
        gemm_r<320,1,1><<<dim3(tilesB), dim3(256), 0, stream>>>(
            msg_cur, nullptr, nullptr, Wt_h + (size_t)d * 320 * 320, nullptr, MW, tilesB);
        comb_k<<<dim3(combGrid), dim3(256), 0, stream>>>(
            MW, input_bond, b_src, b2revb, cnt, bucket, msgA, nB);
        msg_cur = msgA;
    }

    // final per-atom aggregation + product (bf16)
    amsg_k<<<dim3((nA * 40 + 255) / 256), dim3(256), 0, stream>>>(
        msgA, cnt, bucket, input_atom, amsg, prod, nA);

    // atom_h = relu([input_atom | amsg | input_atom*amsg] @ W_o + b_o)
    gemm_r<320,3,2><<<dim3(tilesA), dim3(256), 0, stream>>>(
        input_atom, amsg, prod, Wt_o, b_o, atom_h, tilesA);

    // per-molecule mean
    readout_k<<<dim3(nM), dim3(320), 0, stream>>>(atom_h, mol_ids, nA, (float*)d_out);
}

// Round 11
// 2207.812 us; speedup vs baseline: 1.3133x; 1.2542x over previous
//
#include <hip/hip_runtime.h>
#include <stdint.h>

#define H   300
#define HP  320
#define CAP 32     // max incoming bonds per atom (Binomial(400k,1/200k) max ~13)

using bf8 = __attribute__((ext_vector_type(8))) short;   // 8 x bf16
using s4  = __attribute__((ext_vector_type(4))) short;   // 4 x bf16 (8B store)
using f4  = __attribute__((ext_vector_type(4))) float;   // MFMA acc

__device__ __forceinline__ float bf2f(unsigned short u){
    union { unsigned int i; float f; } v; v.i = ((unsigned int)u) << 16; return v.f;
}
__device__ __forceinline__ unsigned short f2bf(float x){
    unsigned int u = __builtin_bit_cast(unsigned int, x);
    u = (u + 0x7FFFu + ((u >> 16) & 1u)) >> 16;   // RNE
    return (unsigned short)u;
}

// ---------------------------------------------------------------------------
// Incoming-bond bucket list: bucket[a][0..cnt[a]) = bond indices with dst==a
// ---------------------------------------------------------------------------
__global__ void fill_k(const int* __restrict__ b_dst, int* __restrict__ cnt,
                       int* __restrict__ bucket, int nB){
    int e = blockIdx.x * 256 + threadIdx.x;
    if (e >= nB) return;
    int d = b_dst[e];
    int slot = atomicAdd(&cnt[d], 1);
    if (slot < CAP) bucket[(long)d * CAP + slot] = e;
}

// ---------------------------------------------------------------------------
// Weight prep: W [Kact][H] fp32 -> Wt k-major [Ktot/32][320][32] bf16:
// step t, n-row n, k-within kk: Wt[(t*320 + n)*32 + kk] = W[t*32+kk][n]
// (each per-step B panel is a contiguous 20KB block; a wave's 5 frag loads
// each cover a contiguous 1KB run)
// ---------------------------------------------------------------------------
__global__ void prep_wt(const float* __restrict__ W, unsigned short* __restrict__ Wt,
                        int Kact, int Kp){
    int idx = blockIdx.x * 256 + threadIdx.x;
    if (idx >= 320 * Kp) return;
    int t  = idx / (320 * 32);
    int r  = idx % (320 * 32);
    int n  = r / 32, kk = r % 32;
    int k  = t * 32 + kk;
    float v = (n < H && k < Kact) ? W[(long)k * H + n] : 0.f;
    Wt[idx] = f2bf(v);
}

// W_o [900][300] -> k-major [30][320][32]; k = t*32+kk, sec = k/320,
// W row = sec*300 + (k%320); zero-pad k%320 >= 300.
__global__ void prep_wto(const float* __restrict__ W, unsigned short* __restrict__ Wt){
    int idx = blockIdx.x * 256 + threadIdx.x;
    if (idx >= 320 * 960) return;
    int t  = idx / (320 * 32);
    int r  = idx % (320 * 32);
    int n  = r / 32, kk = r % 32;
    int k  = t * 32 + kk;
    int sec = k / HP, ksec = k % HP;
    float v = (n < H && ksec < H) ? W[((long)sec * H + ksec) * H + n] : 0.f;
    Wt[idx] = f2bf(v);
}

// ---------------------------------------------------------------------------
// Input feature conversion: X fp32 [rows][Kact] -> Y bf16 [rows][160] padded
// (linear layout)
// ---------------------------------------------------------------------------
__global__ __launch_bounds__(256)
void conv_in(const float* __restrict__ X, int rows, int Kact,
             unsigned short* __restrict__ Y){
    int t = blockIdx.x * 256 + threadIdx.x;
    if (t >= rows * 20) return;
    int row = t / 20, c = t % 20;
    int k0 = c * 8;
    bf8 v;
    #pragma unroll
    for (int j = 0; j < 8; j++){
        int k = k0 + j;
        float f = (k < Kact) ? X[(long)row * Kact + k] : 0.f;
        v[j] = (short)f2bf(f);
    }
    *(bf8*)(Y + (long)row * 160 + k0) = v;
}

// ---------------------------------------------------------------------------
// GEMM, round-5 structure + upgrades:
//   out[rows][320] = epi( [A0|A1|A2][rows][SEC*RL] @ W^T )
// BM=32, 256 threads = 4 waves, wave tile 32x80, acc = 2x5 f4 (40 AGPR).
// A tile (32 x RL) reg-staged from LINEAR global (contiguous loads) into
// XOR-swizzled LDS once per section; K-loop reads A from LDS (fast), B from
// k-major L2-resident Wt via 2-deep register pipeline. One barrier/section.
// Swapped MFMA (D^T): 8B contiguous epilogue stores (32B-sector aligned).
// __launch_bounds__(256,4) -> <=128 regs/wave -> 4 waves/SIMD resident.
// EPI: 0 = relu, 1 = raw, 2 = relu + b_o.  All buffers LINEAR layout.
// ---------------------------------------------------------------------------
template<int RL, int SEC, int EPI>
__global__ __launch_bounds__(256, 4)
void gemm_k(const unsigned short* __restrict__ A0,
            const unsigned short* __restrict__ A1,
            const unsigned short* __restrict__ A2,
            const unsigned short* __restrict__ Wt,   // k-major [TS][320][32]
            const float* __restrict__ b_o,
            unsigned short* __restrict__ outb,       // [rows][320]
            int nTiles)
{
    constexpr int KS     = RL / 32;        // K-steps per section
    constexpr int TS     = SEC * KS;
    constexpr int CHUNKS = RL / 8;         // 16B chunks per row (40 or 20)
    constexpr int XM     = (RL == 320) ? 7 : 3;
    constexpr int NCH    = 32 * CHUNKS;    // total chunks in tile
    constexpr int ROWB   = RL * 2;         // LDS row stride bytes

    __shared__ char lds[32 * ROWB];        // 20KB (RL=320) / 10KB (RL=160)

    const int tid  = threadIdx.x;
    const int w    = tid >> 6;             // wave -> N stripe of 80
    const int lane = tid & 63;
    const int lr   = lane & 15;
    const int g    = lane >> 4;

    int tile = blockIdx.x;
    if (tile >= nTiles) return;
    const long rowBase = (long)tile * 32;

    const unsigned short* Ap[3] = {A0, A1, A2};

    auto stageA = [&](int sec){
        const char* gb = (const char*)(Ap[sec] + rowBase * RL);
        bf8 st[(NCH + 255) / 256];
        #pragma unroll
        for (int i = 0; i < (NCH + 255) / 256; i++){
            int f = i * 256 + tid;
            if (NCH % 256 == 0 || f < NCH)
                st[i] = *(const bf8*)(gb + f * 16);
        }
        #pragma unroll
        for (int i = 0; i < (NCH + 255) / 256; i++){
            int f = i * 256 + tid;
            if (NCH % 256 == 0 || f < NCH){
                int row = f / CHUNKS, c = f % CHUNKS;
                *(bf8*)(lds + row * ROWB + ((c ^ (row & XM)) << 4)) = st[i];
            }
        }
    };

    bf8 bb[2][5];
    auto loadB = [&](int t, bf8 (&dst)[5]){
        const unsigned short* base = Wt + ((long)t * 320) * 32 + g * 8;
        #pragma unroll
        for (int n = 0; n < 5; n++)
            dst[n] = *(const bf8*)(base + (w * 80 + n * 16 + lr) * 32);
    };

    f4 acc[2][5];

    #pragma unroll
    for (int sec = 0; sec < SEC; ++sec){
        if (sec > 0) __syncthreads();      // readers done with LDS
        stageA(sec);
        __syncthreads();
        if (sec == 0){
            #pragma unroll
            for (int m = 0; m < 2; m++)
                #pragma unroll
                for (int n = 0; n < 5; n++)
                    acc[m][n] = (f4){0.f, 0.f, 0.f, 0.f};
        }
        loadB(sec * KS + 0, bb[0]);
        if (KS > 1) loadB(sec * KS + 1, bb[1]);

        #pragma unroll
        for (int i = 0; i < KS; i++){
            bf8 af[2];
            #pragma unroll
            for (int m = 0; m < 2; m++){
                int row = m * 16 + lr;
                int ch  = i * 4 + g;
                af[m] = *(const bf8*)(lds + row * ROWB + ((ch ^ (row & XM)) << 4));
            }
            #pragma unroll
            for (int m = 0; m < 2; m++)
                #pragma unroll
                for (int n = 0; n < 5; n++)
                    acc[m][n] = __builtin_amdgcn_mfma_f32_16x16x32_bf16(
                        bb[i & 1][n], af[m], acc[m][n], 0, 0, 0);
            if (i + 2 < KS) loadB(sec * KS + i + 2, bb[i & 1]);
        }
    }

    // epilogue: D^T -> lane holds output row lr(+16m), 4 consecutive cols
    #pragma unroll
    for (int m = 0; m < 2; m++){
        const long row = rowBase + m * 16 + lr;
        #pragma unroll
        for (int n = 0; n < 5; n++){
            const int colBase = w * 80 + n * 16 + g * 4;
            s4 v4;
            #pragma unroll
            for (int q = 0; q < 4; q++){
                int col = colBase + q;
                float v = acc[m][n][q];
                if constexpr (EPI == 2) v += (col < H ? b_o[col] : 0.f);
                if constexpr (EPI != 1) v = fmaxf(v, 0.f);
                v4[q] = (short)f2bf(v);
            }
            *(s4*)(outb + row * HP + colBase) = v4;
        }
    }
}

// ---------------------------------------------------------------------------
// comb: msg'[e] = relu(bond_in[e] + sum_{j in bucket[src[e]]} MW[j] - MW[rev[e]])
// thread = (bond, 16B chunk); 6 independent loads in flight. Linear layout.
// ---------------------------------------------------------------------------
__global__ __launch_bounds__(256)
void comb_k(const unsigned short* __restrict__ MW,
            const unsigned short* __restrict__ bond_in,
            const int* __restrict__ b_src, const int* __restrict__ b2revb,
            const int* __restrict__ cnt, const int* __restrict__ bucket,
            unsigned short* __restrict__ out, int nB){
    int t = blockIdx.x * 256 + threadIdx.x;
    if (t >= nB * 40) return;
    int e = t / 40, ch = t % 40;
    int k0 = ch * 8;
    int s   = b_src[e];
    int rev = b2revb[e];
    int dg = cnt[s]; if (dg > CAP) dg = CAP;
    long base = (long)s * CAP;
    int be0 = 0, be1 = 0, be2 = 0, be3 = 0;
    if (dg > 0) be0 = bucket[base + 0];
    if (dg > 1) be1 = bucket[base + 1];
    if (dg > 2) be2 = bucket[base + 2];
    if (dg > 3) be3 = bucket[base + 3];
    bf8 bi = *(const bf8*)(bond_in + (long)e * HP + k0);
    bf8 rv = *(const bf8*)(MW + (long)rev * HP + k0);
    bf8 m0, m1, m2, m3;
    if (dg > 0) m0 = *(const bf8*)(MW + (long)be0 * HP + k0);
    if (dg > 1) m1 = *(const bf8*)(MW + (long)be1 * HP + k0);
    if (dg > 2) m2 = *(const bf8*)(MW + (long)be2 * HP + k0);
    if (dg > 3) m3 = *(const bf8*)(MW + (long)be3 * HP + k0);
    float sacc[8];
    #pragma unroll
    for (int q = 0; q < 8; q++)
        sacc[q] = bf2f((unsigned short)bi[q]) - bf2f((unsigned short)rv[q]);
    auto addv = [&](bf8 mm){
        #pragma unroll
        for (int q = 0; q < 8; q++) sacc[q] += bf2f((unsigned short)mm[q]);
    };
    if (dg > 0) addv(m0);
    if (dg > 1) addv(m1);
    if (dg > 2) addv(m2);
    if (dg > 3) addv(m3);
    for (int j = 4; j < dg; ++j){
        int be = bucket[base + j];
        addv(*(const bf8*)(MW + (long)be * HP + k0));
    }
    bf8 v;
    #pragma unroll
    for (int q = 0; q < 8; q++) v[q] = (short)f2bf(fmaxf(sacc[q], 0.f));
    *(bf8*)(out + (long)e * HP + k0) = v;
}

// ---------------------------------------------------------------------------
// a_msg[a] = sum of msg rows with dst==a; also prod[a] = a_msg[a] * input_atom[a]
// ---------------------------------------------------------------------------
__global__ __launch_bounds__(256)
void amsg_k(const unsigned short* __restrict__ msg, const int* __restrict__ cnt,
            const int* __restrict__ bucket,
            const unsigned short* __restrict__ input_atom,
            unsigned short* __restrict__ amsg, unsigned short* __restrict__ prod,
            int nA){
    int t = blockIdx.x * 256 + threadIdx.x;
    if (t >= nA * 40) return;
    int a = t / 40, ch = t % 40;
    int k0 = ch * 8;
    int dg = cnt[a]; if (dg > CAP) dg = CAP;
    long base = (long)a * CAP;
    int be0 = 0, be1 = 0, be2 = 0, be3 = 0;
    if (dg > 0) be0 = bucket[base + 0];
    if (dg > 1) be1 = bucket[base + 1];
    if (dg > 2) be2 = bucket[base + 2];
    if (dg > 3) be3 = bucket[base + 3];
    bf8 ia = *(const bf8*)(input_atom + (long)a * HP + k0);
    bf8 m0, m1, m2, m3;
    if (dg > 0) m0 = *(const bf8*)(msg + (long)be0 * HP + k0);
    if (dg > 1) m1 = *(const bf8*)(msg + (long)be1 * HP + k0);
    if (dg > 2) m2 = *(const bf8*)(msg + (long)be2 * HP + k0);
    if (dg > 3) m3 = *(const bf8*)(msg + (long)be3 * HP + k0);
    float s[8];
    #pragma unroll
    for (int q = 0; q < 8; q++) s[q] = 0.f;
    auto addv = [&](bf8 mm){
        #pragma unroll
        for (int q = 0; q < 8; q++) s[q] += bf2f((unsigned short)mm[q]);
    };
    if (dg > 0) addv(m0);
    if (dg > 1) addv(m1);
    if (dg > 2) addv(m2);
    if (dg > 3) addv(m3);
    for (int j = 4; j < dg; ++j)
        addv(*(const bf8*)(msg + (long)bucket[base + j] * HP + k0));
    bf8 va, vp;
    #pragma unroll
    for (int q = 0; q < 8; q++){
        va[q] = (short)f2bf(s[q]);
        vp[q] = (short)f2bf(s[q] * bf2f((unsigned short)ia[q]));
    }
    *(bf8*)(amsg + (long)a * HP + k0) = va;
    *(bf8*)(prod + (long)a * HP + k0) = vp;
}

// ---------------------------------------------------------------------------
// Readout: per-molecule mean over sorted mol_ids (binary-search range)
// ---------------------------------------------------------------------------
__global__ __launch_bounds__(320)
void readout_k(const unsigned short* __restrict__ atom_h,
               const int* __restrict__ mol_ids, int nAtoms,
               float* __restrict__ out){
    int m = blockIdx.x;
    int t = threadIdx.x;
    int lo = 0, hi = nAtoms;
    while (lo < hi){ int mid = (lo + hi) >> 1; if (mol_ids[mid] < m) lo = mid + 1; else hi = mid; }
    int lo2 = lo, hi2 = nAtoms;
    while (lo2 < hi2){ int mid = (lo2 + hi2) >> 1; if (mol_ids[mid] < m + 1) lo2 = mid + 1; else hi2 = mid; }
    if (t < H){
        float s = 0.f;
        for (int a = lo; a < lo2; ++a) s += bf2f(atom_h[(long)a * HP + t]);
        int c2 = lo2 - lo;
        out[(long)m * H + t] = s / (float)(c2 > 0 ? c2 : 1);
    }
}

// ---------------------------------------------------------------------------
extern "C" void kernel_launch(void* const* d_in, const int* in_sizes, int n_in,
                              void* d_out, int out_size, void* d_ws, size_t ws_size,
                              hipStream_t stream){
    const float* f_atoms  = (const float*)d_in[0];
    const float* f_bonds  = (const float*)d_in[1];
    const float* W_i_atom = (const float*)d_in[2];
    const float* W_i_bond = (const float*)d_in[3];
    const float* W_h      = (const float*)d_in[4];
    const float* W_o      = (const float*)d_in[5];
    const float* b_o      = (const float*)d_in[6];
    const int* b_src   = (const int*)d_in[7];
    const int* b_dst   = (const int*)d_in[8];
    const int* b2revb  = (const int*)d_in[9];
    const int* mol_ids = (const int*)d_in[10];

    const int nA = in_sizes[10];          // 200000
    const int nB = in_sizes[7];           // 400000
    const int nM = out_size / H;          // 4096

    char* p = (char*)d_ws;
    auto alloc = [&](size_t bytes){ char* q = p; p += (bytes + 255) & ~(size_t)255; return q; };
    unsigned short* Wt_ia = (unsigned short*)alloc((size_t)320 * 160 * 2);
    unsigned short* Wt_ib = (unsigned short*)alloc((size_t)320 * 160 * 2);
    unsigned short* Wt_h  = (unsigned short*)alloc((size_t)3 * 320 * 320 * 2);
    unsigned short* Wt_o  = (unsigned short*)alloc((size_t)320 * 960 * 2);
    int* cnt    = (int*)alloc((size_t)nA * 4);
    int* bucket = (int*)alloc((size_t)nA * CAP * 4);
    unsigned short* input_atom = (unsigned short*)alloc((size_t)nA * HP * 2);
    unsigned short* input_bond = (unsigned short*)alloc((size_t)nB * HP * 2);
    unsigned short* msgA = (unsigned short*)alloc((size_t)nB * HP * 2);
    unsigned short* MW   = (unsigned short*)alloc((size_t)nB * HP * 2);
    // aliases into dead regions:
    unsigned short* fa_bf  = MW;                                  // [nA][160], dead before MW first written
    unsigned short* fb_bf  = MW + (size_t)nA * 160;               // [nB][160]
    unsigned short* amsg   = MW;                                  // MW dead after comb3
    unsigned short* prod   = MW + (size_t)nA * HP;
    unsigned short* atom_h = input_bond;                          // dead after comb3

    if ((size_t)(p - (char*)d_ws) > ws_size) return;  // diagnostic: ws too small

    // adjacency buckets
    hipMemsetAsync(cnt, 0, (size_t)nA * 4, stream);
    fill_k<<<dim3((nB + 255) / 256), dim3(256), 0, stream>>>(b_dst, cnt, bucket, nB);

    // weight prep (k-major) + input conversion (linear)
    prep_wt<<<dim3((320*160 + 255)/256), dim3(256), 0, stream>>>(W_i_atom, Wt_ia, 133, 160);
    prep_wt<<<dim3((320*160 + 255)/256), dim3(256), 0, stream>>>(W_i_bond, Wt_ib, 147, 160);
    for (int d = 0; d < 3; d++)
        prep_wt<<<dim3((320*320 + 255)/256), dim3(256), 0, stream>>>(
            W_h + (size_t)d * H * H, Wt_h + (size_t)d * 320 * 320, 300, 320);
    prep_wto<<<dim3((320*960 + 255)/256), dim3(256), 0, stream>>>(W_o, Wt_o);
    conv_in<<<dim3((nA*20 + 255)/256), dim3(256), 0, stream>>>(f_atoms, nA, 133, fa_bf);
    conv_in<<<dim3((nB*20 + 255)/256), dim3(256), 0, stream>>>(f_bonds, nB, 147, fb_bf);

    const int tilesA = nA / 32, tilesB = nB / 32;

    // input projections
    gemm_k<160,1,0><<<dim3(tilesA), dim3(256), 0, stream>>>(
        fa_bf, nullptr, nullptr, Wt_ia, nullptr, input_atom, tilesA);
    gemm_k<160,1,0><<<dim3(tilesB), dim3(256), 0, stream>>>(
        fb_bf, nullptr, nullptr, Wt_ib, nullptr, input_bond, tilesB);

    // message steps: MW = msg @ W_h[d]; msg' = relu(bond_in + bucket-sum - rev)
    const int combGrid = (nB * 40 + 255) / 256;
    const unsigned short* msg_cur = input_bond;
    for (int d = 0; d < 3; d++){
        gemm_k<320,1,1><<<dim3(tilesB), dim3(256), 0, stream>>>(
            msg_cur, nullptr, nullptr, Wt_h + (size_t)d * 320 * 320, nullptr, MW, tilesB);
        comb_k<<<dim3(combGrid), dim3(256), 0, stream>>>(
            MW, input_bond, b_src, b2revb, cnt, bucket, msgA, nB);
        msg_cur = msgA;
    }

    // final per-atom aggregation + product (bf16)
    amsg_k<<<dim3((nA * 40 + 255) / 256), dim3(256), 0, stream>>>(
        msgA, cnt, bucket, input_atom, amsg, prod, nA);

    // atom_h = relu([input_atom | amsg | input_atom*amsg] @ W_o + b_o)
    gemm_k<320,3,2><<<dim3(tilesA), dim3(256), 0, stream>>>(
        input_atom, amsg, prod, Wt_o, b_o, atom_h, tilesA);

    // per-molecule mean
    readout_k<<<dim3(nM), dim3(320), 0, stream>>>(atom_h, mol_ids, nA, (float*)d_out);
}